// Round 4
// baseline (485.036 us; speedup 1.0000x reference)
//
#include <hip/hip_runtime.h>
#include <stdint.h>

#define N_NODES 50000
#define N_EDGES 800000
#define NFEAT   16
#define EFEAT   8
#define HID     64
#define OUTF    8
#define NMID    2
#define NX      (N_NODES * NFEAT)
#define NPW     16                                     // nodes per wave (gemm kernels)
#define CAP     64                                     // bucket capacity (max deg ~45)
#define PGB     ((N_NODES + 4 * NPW - 1) / (4 * NPW))  // 782 blocks (gemm)
#define PPB     ((N_NODES + 15) / 16)                  // 3125 blocks (prop: 4 nodes/wave)
#define NWB     ((N_NODES + 3) / 4)                    // 12500 blocks (wave-per-node)

typedef unsigned short ushort_t;
typedef unsigned int   uint_t;
typedef unsigned long long ull_t;
typedef __bf16 bf16x8 __attribute__((ext_vector_type(8)));
typedef float  f32x4  __attribute__((ext_vector_type(4)));

__device__ __forceinline__ float b2f(ushort_t u) {
    return __uint_as_float(((uint_t)u) << 16);
}
__device__ __forceinline__ ushort_t f2b(float f) {
    uint_t u = __float_as_uint(f);
    return (ushort_t)((u + 0x7fffu + ((u >> 16) & 1u)) >> 16);
}
// fp16 (IEEE half) pack/unpack via native _Float16
__device__ __forceinline__ float h2f(ushort_t u) {
    union { ushort_t u; _Float16 h; } c; c.u = u; return (float)c.h;
}
__device__ __forceinline__ ushort_t f2h(float f) {
    union { ushort_t u; _Float16 h; } c; c.h = (_Float16)f; return c.u;
}

// ---------- edge MLP (1 edge/thread) + fused x->bf16 + 8B {ew,src} scatter ----------
// W1/b1/W2/b2 are wave-uniform -> s_load + SGPR-operand v_fma (no LDS).
// Bucket entries are 8B {fp32 ew | u32 src}: scattered-write line traffic is the
// same (one 64B line per edge either way), but it removes ALL random ew/ei
// gathers from degdinv/rescale (they become linear readers).
__global__ __launch_bounds__(256) void edge_mlp_kernel(
    const float* __restrict__ ea, const float* __restrict__ x,
    const int* __restrict__ ei,
    const float* __restrict__ W1, const float* __restrict__ b1,
    const float* __restrict__ W2, const float* __restrict__ b2,
    ushort_t* __restrict__ xb,
    int* __restrict__ cnts, ull_t* __restrict__ bucket8)
{
    int tid = threadIdx.x;
    int e = blockIdx.x * 256 + tid;          // grid covers N_EDGES == NX exactly
    if (e >= N_EDGES) return;

    // atomic first: its round trip hides under the MLP below
    int d = ei[N_EDGES + e];
    int pos = atomicAdd(&cnts[d], 1);
    int sn = ei[e];                          // src, linear read

    xb[e] = f2b(x[e]);                       // fused x convert (same index space)

    // ---- MLP: fp32 exact, SGPR weights ----
    float4 v0 = ((const float4*)ea)[2 * e];
    float4 v1 = ((const float4*)ea)[2 * e + 1];
    float a[8] = {v0.x, v0.y, v0.z, v0.w, v1.x, v1.y, v1.z, v1.w};

    float h[HID];
    #pragma unroll
    for (int j = 0; j < HID; ++j) h[j] = b1[j];          // uniform -> s_load

    #pragma unroll
    for (int i = 0; i < EFEAT; ++i) {
        float ai = a[i];
        #pragma unroll
        for (int j = 0; j < HID; ++j)
            h[j] = fmaf(ai, W1[i * HID + j], h[j]);      // uniform W1 -> SGPR operand
    }

    float acc = b2[0];
    #pragma unroll
    for (int j = 0; j < HID; ++j)
        acc = fmaf(fmaxf(h[j], 0.f), W2[j], acc);        // uniform W2 -> SGPR operand

    if (pos < CAP)
        bucket8[(size_t)d * CAP + pos] =
            (((ull_t)__float_as_uint(acc)) << 32) | (uint_t)sn;
}

// ---------- deg (fp32-exact sum of ew, linear bucket8 read) -> dinv ----------
__global__ __launch_bounds__(256) void degdinv_kernel(
    int* __restrict__ cnts, const ull_t* __restrict__ bucket8,
    float* __restrict__ dinv)
{
    int tid = threadIdx.x;
    int n = blockIdx.x * 4 + (tid >> 6);
    int lane = tid & 63;
    if (n >= N_NODES) return;
    int c = cnts[n]; if (c > CAP) c = CAP;
    float w = 0.f;
    if (lane < c)
        w = __uint_as_float((uint_t)(bucket8[(size_t)n * CAP + lane] >> 32));
    #pragma unroll
    for (int o = 32; o; o >>= 1) w += __shfl_down(w, o, 64);
    if (lane == 0) {
        cnts[n] = c;
        dinv[n] = (w > 0.f) ? (1.f / sqrtf(w)) : 0.f;
    }
}

// ---------- rescale: bucket8 (linear) -> bucket4 (fp16 norm << 16 | u16 src) ----------
__global__ __launch_bounds__(256) void rescale_kernel(
    const int* __restrict__ cnts, const float* __restrict__ dinv,
    const ull_t* __restrict__ bucket8, uint_t* __restrict__ bucket4)
{
    int tid = threadIdx.x;
    int n = blockIdx.x * 4 + (tid >> 6);
    int lane = tid & 63;
    if (n >= N_NODES) return;
    int c = cnts[n];
    float dn = dinv[n];
    if (lane < c) {
        ull_t q = bucket8[(size_t)n * CAP + lane];
        uint_t s = (uint_t)q;                           // src < 65536? no: < 50000 ✓
        float ewv = __uint_as_float((uint_t)(q >> 32));
        float nv = dinv[s] * ewv * dn;
        nv = fminf(fmaxf(nv, -60000.f), 60000.f);       // fp16 range guard
        bucket4[(size_t)n * CAP + lane] = (((uint_t)f2h(nv)) << 16) | s;
    }
}

// ---------- pure propagation: 4 nodes/wave (widths 64 and 16), 4B entries ----------
// Branchless padded edge loops (zero bucket word -> nv = 0.0 -> no-op FMA).
// W=64 path: explicit 2-stage register pipeline (32 gathers in flight).
// Edge words live in SGPRs (readlane results); only h-floats occupy VGPRs.
template<int W>
__global__ __launch_bounds__(256, 6) void prop_kernel(
    const ushort_t* __restrict__ gsrc, ushort_t* __restrict__ gout,
    const int* __restrict__ cnts, const uint_t* __restrict__ bucket)
{
    int tid = threadIdx.x;
    int wv = tid >> 6, lane = tid & 63;
    int nb = (blockIdx.x * 4 + wv) * 4;
    if (nb >= N_NODES) return;

    int cv = (lane < 4) ? cnts[nb + lane] : 0;
    int c0 = __builtin_amdgcn_readlane(cv, 0);
    int c1 = __builtin_amdgcn_readlane(cv, 1);
    int c2 = __builtin_amdgcn_readlane(cv, 2);
    int c3 = __builtin_amdgcn_readlane(cv, 3);
    int cm = max(max(c0, c1), max(c2, c3));

    uint_t p0 = 0, p1 = 0, p2 = 0, p3 = 0;
    if (lane < c0) p0 = bucket[(size_t)(nb + 0) * CAP + lane];
    if (lane < c1) p1 = bucket[(size_t)(nb + 1) * CAP + lane];
    if (lane < c2) p2 = bucket[(size_t)(nb + 2) * CAP + lane];
    if (lane < c3) p3 = bucket[(size_t)(nb + 3) * CAP + lane];

    if (W == 64) {
        float s[4][4];
        #pragma unroll
        for (int n = 0; n < 4; ++n)
            #pragma unroll
            for (int k = 0; k < 4; ++k) s[n][k] = 0.f;

        float hvA[16], hvB[16];
        int   peA[16], peB[16];

        // load 16 gathers for quad-step J (J+k <= 63 always: J <= 60)
        #define LOADQ(HV, PE, J)                                                     \
            { _Pragma("unroll")                                                      \
              for (int k = 0; k < 4; ++k) {                                          \
                  PE[0*4+k] = __builtin_amdgcn_readlane((int)p0, (J) + k);           \
                  PE[1*4+k] = __builtin_amdgcn_readlane((int)p1, (J) + k);           \
                  PE[2*4+k] = __builtin_amdgcn_readlane((int)p2, (J) + k);           \
                  PE[3*4+k] = __builtin_amdgcn_readlane((int)p3, (J) + k);           \
                  HV[0*4+k] = b2f(gsrc[(size_t)(PE[0*4+k] & 0xffff) * 64 + lane]);   \
                  HV[1*4+k] = b2f(gsrc[(size_t)(PE[1*4+k] & 0xffff) * 64 + lane]);   \
                  HV[2*4+k] = b2f(gsrc[(size_t)(PE[2*4+k] & 0xffff) * 64 + lane]);   \
                  HV[3*4+k] = b2f(gsrc[(size_t)(PE[3*4+k] & 0xffff) * 64 + lane]);   \
              } }

        #define FMAQ(HV, PE)                                                         \
            { _Pragma("unroll")                                                      \
              for (int n = 0; n < 4; ++n)                                            \
                  _Pragma("unroll")                                                  \
                  for (int k = 0; k < 4; ++k)                                        \
                      s[n][k] = fmaf(HV[n*4+k],                                      \
                          h2f((ushort_t)(((uint_t)PE[n*4+k]) >> 16)), s[n][k]); }

        int nsteps = (cm + 3) >> 2;       // <= 16
        if (nsteps > 0) {
            LOADQ(hvA, peA, 0)
            for (int t = 1; t < nsteps; t += 2) {
                LOADQ(hvB, peB, t * 4)
                FMAQ(hvA, peA)
                if (t + 1 < nsteps) LOADQ(hvA, peA, (t + 1) * 4)
                FMAQ(hvB, peB)
            }
            if (nsteps & 1) FMAQ(hvA, peA)
        }
        #undef LOADQ
        #undef FMAQ

        #pragma unroll
        for (int n = 0; n < 4; ++n) {
            float v = (s[n][0] + s[n][1]) + (s[n][2] + s[n][3]);
            gout[(size_t)(nb + n) * 64 + lane] = f2b(v);
        }
    } else {
        const int il = lane & 15;
        const int quad = lane >> 4;
        float s0 = 0.f, s1 = 0.f, s2 = 0.f, s3 = 0.f;

        // j <= 60 (multiple of 4, j < cm <= 64), quad <= 3 -> jq <= 63
        #pragma unroll 2
        for (int j = 0; j < cm; j += 4) {
            int jq = j + quad;
            int w0 = __shfl((int)p0, jq, 64);
            int w1 = __shfl((int)p1, jq, 64);
            int w2 = __shfl((int)p2, jq, 64);
            int w3 = __shfl((int)p3, jq, 64);
            float h0 = b2f(gsrc[(size_t)(w0 & 0xffff) * 16 + il]);
            float h1 = b2f(gsrc[(size_t)(w1 & 0xffff) * 16 + il]);
            float h2 = b2f(gsrc[(size_t)(w2 & 0xffff) * 16 + il]);
            float h3 = b2f(gsrc[(size_t)(w3 & 0xffff) * 16 + il]);
            s0 = fmaf(h0, h2f((ushort_t)(((uint_t)w0) >> 16)), s0);
            s1 = fmaf(h1, h2f((ushort_t)(((uint_t)w1) >> 16)), s1);
            s2 = fmaf(h2, h2f((ushort_t)(((uint_t)w2) >> 16)), s2);
            s3 = fmaf(h3, h2f((ushort_t)(((uint_t)w3) >> 16)), s3);
        }

        s0 += __shfl_xor(s0, 16, 64); s0 += __shfl_xor(s0, 32, 64);
        s1 += __shfl_xor(s1, 16, 64); s1 += __shfl_xor(s1, 32, 64);
        s2 += __shfl_xor(s2, 16, 64); s2 += __shfl_xor(s2, 32, 64);
        s3 += __shfl_xor(s3, 16, 64); s3 += __shfl_xor(s3, 32, 64);
        if (lane < 16) {
            gout[(size_t)(nb + 0) * 16 + lane] = f2b(s0);
            gout[(size_t)(nb + 1) * 16 + lane] = f2b(s1);
            gout[(size_t)(nb + 2) * 16 + lane] = f2b(s2);
            gout[(size_t)(nb + 3) * 16 + lane] = f2b(s3);
        }
    }
}

// ---------- width-8 Horner propagation: out[n] = A·gsrc + add  (octet per edge) ----------
template<int F32OUT>
__global__ __launch_bounds__(256, 8) void prop8_kernel(
    const ushort_t* __restrict__ gsrc, int GS, int GO,
    const ushort_t* __restrict__ add, int AS, int AO,
    ushort_t* __restrict__ outb, float* __restrict__ outf,
    const int* __restrict__ cnts, const uint_t* __restrict__ bucket)
{
    int tid = threadIdx.x;
    int wv = tid >> 6, lane = tid & 63;
    int nb = (blockIdx.x * 4 + wv) * 4;
    if (nb >= N_NODES) return;
    const int oct = lane >> 3, il = lane & 7;

    int cv = (lane < 4) ? cnts[nb + lane] : 0;
    int c0 = __builtin_amdgcn_readlane(cv, 0);
    int c1 = __builtin_amdgcn_readlane(cv, 1);
    int c2 = __builtin_amdgcn_readlane(cv, 2);
    int c3 = __builtin_amdgcn_readlane(cv, 3);
    int cm = max(max(c0, c1), max(c2, c3));

    uint_t p0 = 0, p1 = 0, p2 = 0, p3 = 0;
    if (lane < c0) p0 = bucket[(size_t)(nb + 0) * CAP + lane];
    if (lane < c1) p1 = bucket[(size_t)(nb + 1) * CAP + lane];
    if (lane < c2) p2 = bucket[(size_t)(nb + 2) * CAP + lane];
    if (lane < c3) p3 = bucket[(size_t)(nb + 3) * CAP + lane];

    float s0 = 0.f, s1 = 0.f, s2 = 0.f, s3 = 0.f;

    // j <= 56 (multiple of 8, j < cm <= 64), oct <= 7 -> jo <= 63
    #pragma unroll 2
    for (int j = 0; j < cm; j += 8) {
        int jo = j + oct;
        int w0 = __shfl((int)p0, jo, 64);
        int w1 = __shfl((int)p1, jo, 64);
        int w2 = __shfl((int)p2, jo, 64);
        int w3 = __shfl((int)p3, jo, 64);
        float h0 = b2f(gsrc[(size_t)(w0 & 0xffff) * GS + GO + il]);
        float h1 = b2f(gsrc[(size_t)(w1 & 0xffff) * GS + GO + il]);
        float h2 = b2f(gsrc[(size_t)(w2 & 0xffff) * GS + GO + il]);
        float h3 = b2f(gsrc[(size_t)(w3 & 0xffff) * GS + GO + il]);
        s0 = fmaf(h0, h2f((ushort_t)(((uint_t)w0) >> 16)), s0);
        s1 = fmaf(h1, h2f((ushort_t)(((uint_t)w1) >> 16)), s1);
        s2 = fmaf(h2, h2f((ushort_t)(((uint_t)w2) >> 16)), s2);
        s3 = fmaf(h3, h2f((ushort_t)(((uint_t)w3) >> 16)), s3);
    }

    #define FIN(sN, n)                                                               \
        {                                                                            \
            float s = sN;                                                            \
            s += __shfl_xor(s, 8, 64);                                               \
            s += __shfl_xor(s, 16, 64);                                              \
            s += __shfl_xor(s, 32, 64);                                              \
            if (lane < 8) {                                                          \
                float v = s + b2f(add[(size_t)(nb + n) * AS + AO + lane]);           \
                if (F32OUT) outf[(size_t)(nb + n) * 8 + lane] = v;                   \
                else        outb[(size_t)(nb + n) * 8 + lane] = f2b(v);              \
            }                                                                        \
        }
    FIN(s0, 0)
    FIN(s1, 1)
    FIN(s2, 2)
    FIN(s3, 3)
    #undef FIN
}

// ---------- dense 4-source MFMA GEMM: out = act(bias + sum_s src_s @ W_s) ----------
template<int SRCW, int COUT, int ACT>
__global__ __launch_bounds__(256, 4) void gemm4_kernel(
    const ushort_t* __restrict__ s0, const ushort_t* __restrict__ s1,
    const ushort_t* __restrict__ s2, const ushort_t* __restrict__ s3,
    const float* __restrict__ Wg,    // (4, SRCW, COUT) fp32
    const float* __restrict__ bias,
    ushort_t* __restrict__ outb)
{
    constexpr int NCH = (SRCW == 16) ? 2 : 8;
    constexpr int NT  = (COUT + 15) / 16;
    __shared__ __align__(16) ushort_t Bp[NCH * NT * 512];

    int tid = threadIdx.x;
    for (int idx = tid; idx < NCH * NT * 512; idx += 256) {
        int f = idx >> 9;
        int l = (idx >> 3) & 63, j = idx & 7;
        int ch = f / NT, nt = f - ch * NT;
        int kk = ((l >> 4) << 3) + j;       // 0..31
        int n = nt * 16 + (l & 15);
        int widx, krow;
        if (SRCW == 16) { widx = 2 * ch + (kk >> 4); krow = kk & 15; }
        else            { widx = ch >> 1;            krow = ((ch & 1) << 5) + kk; }
        float v = (n < COUT) ? Wg[((size_t)widx * SRCW + krow) * COUT + n] : 0.f;
        Bp[idx] = f2b(v);
    }
    __syncthreads();

    int wv = tid >> 6, lane = tid & 63;
    int node_base = (blockIdx.x * 4 + wv) * NPW;
    if (node_base >= N_NODES) return;
    int m = lane & 15, quad = lane >> 4;

    const ushort_t* srcs[4] = {s0, s1, s2, s3};
    bf16x8 a[NCH];
    #pragma unroll
    for (int ch = 0; ch < NCH; ++ch) {
        const ushort_t* sp;
        size_t off;
        if (SRCW == 16) {
            sp = (quad < 2) ? srcs[2 * ch] : srcs[2 * ch + 1];
            off = (size_t)(node_base + m) * 16 + (quad & 1) * 8;
        } else {
            sp = srcs[ch >> 1];
            off = (size_t)(node_base + m) * 64 + ((ch & 1) << 5) + quad * 8;
        }
        a[ch] = *(const bf16x8*)(sp + off);
    }

    #pragma unroll
    for (int nt = 0; nt < NT; ++nt) {
        float bv = bias[(nt * 16 + m) & (COUT - 1)];
        f32x4 c = {bv, bv, bv, bv};
        #pragma unroll
        for (int ch = 0; ch < NCH; ++ch) {
            bf16x8 b = *(const bf16x8*)&Bp[((ch * NT + nt) * 64 + lane) * 8];
            c = __builtin_amdgcn_mfma_f32_16x16x32_bf16(a[ch], b, c, 0, 0, 0);
        }
        #pragma unroll
        for (int r = 0; r < 4; ++r) {
            int row = node_base + quad * 4 + r;
            float v = ACT ? fmaxf(c[r], 0.f) : c[r];
            outb[(size_t)row * COUT + nt * 16 + m] = f2b(v);
        }
    }
}

// ---------- last-layer Z pack: Z[n][4*8] = [cin@Wl0 + bl | cin@Wl1 | cin@Wl2 | cin@Wl3] ----------
__global__ __launch_bounds__(256, 4) void gemmL_kernel(
    const ushort_t* __restrict__ src,   // 50k x 64 bf16
    const float* __restrict__ Wl,       // (4, 64, 8) fp32
    const float* __restrict__ bl,       // (8)
    ushort_t* __restrict__ Z)           // 50k x 32 bf16
{
    __shared__ __align__(16) ushort_t Bp[2 * 2 * 512];

    int tid = threadIdx.x;
    for (int idx = tid; idx < 2048; idx += 256) {
        int f = idx >> 9;                   // 0..3
        int ch = f >> 1, nt = f & 1;
        int l = (idx >> 3) & 63, j = idx & 7;
        int kg = ch * 32 + ((l >> 4) << 3) + j;   // 0..63
        int n = nt * 16 + (l & 15);               // 0..31
        int widx = n >> 3, col = n & 7;
        Bp[idx] = f2b(Wl[((size_t)widx * 64 + kg) * 8 + col]);
    }
    __syncthreads();

    int wv = tid >> 6, lane = tid & 63;
    int node_base = (blockIdx.x * 4 + wv) * NPW;
    if (node_base >= N_NODES) return;
    int m = lane & 15, quad = lane >> 4;

    bf16x8 a[2];
    #pragma unroll
    for (int ch = 0; ch < 2; ++ch)
        a[ch] = *(const bf16x8*)(src + (size_t)(node_base + m) * 64 + ch * 32 + quad * 8);

    #pragma unroll
    for (int nt = 0; nt < 2; ++nt) {
        int n = nt * 16 + m;
        float bv = (n < 8) ? bl[n] : 0.f;   // bias folded into z0 block
        f32x4 c = {bv, bv, bv, bv};
        #pragma unroll
        for (int ch = 0; ch < 2; ++ch) {
            bf16x8 b = *(const bf16x8*)&Bp[((ch * 2 + nt) * 64 + lane) * 8];
            c = __builtin_amdgcn_mfma_f32_16x16x32_bf16(a[ch], b, c, 0, 0, 0);
        }
        #pragma unroll
        for (int r = 0; r < 4; ++r) {
            int row = node_base + quad * 4 + r;
            Z[(size_t)row * 32 + n] = f2b(c[r]);
        }
    }
}

extern "C" void kernel_launch(void* const* d_in, const int* in_sizes, int n_in,
                              void* d_out, int out_size, void* d_ws, size_t ws_size,
                              hipStream_t stream)
{
    const float* x  = (const float*)d_in[0];
    const int*   ei = (const int*)d_in[1];
    const float* ea = (const float*)d_in[2];
    const float* W1 = (const float*)d_in[3];
    const float* b1 = (const float*)d_in[4];
    const float* W2 = (const float*)d_in[5];
    const float* b2 = (const float*)d_in[6];
    const float* Wf = (const float*)d_in[7];
    const float* bf = (const float*)d_in[8];
    const float* Wm = (const float*)d_in[9];
    const float* bm = (const float*)d_in[10];
    const float* Wl = (const float*)d_in[11];
    const float* bl = (const float*)d_in[12];

    char* ws = (char*)d_ws;
    size_t off = 0;
    auto take = [&](size_t bytes) -> char* {
        char* p = ws + off;
        off = (off + bytes + 255) & ~(size_t)255;
        return p;
    };
    int*      cnts    = (int*)take((size_t)N_NODES * 4);
    float*    dinv    = (float*)take((size_t)N_NODES * 4);
    ull_t*    bucket8 = (ull_t*)take((size_t)N_NODES * CAP * 8);
    uint_t*   bucket4 = (uint_t*)take((size_t)N_NODES * CAP * 4);
    ushort_t* xb      = (ushort_t*)take((size_t)NX * 2 + 256);
    ushort_t* g1      = (ushort_t*)take((size_t)N_NODES * HID * 2 + 256);
    ushort_t* g2      = (ushort_t*)take((size_t)N_NODES * HID * 2 + 256);
    ushort_t* g3      = (ushort_t*)take((size_t)N_NODES * HID * 2 + 256);
    ushort_t* curA    = (ushort_t*)take((size_t)N_NODES * HID * 2 + 256);
    ushort_t* curB    = (ushort_t*)take((size_t)N_NODES * HID * 2 + 256);
    ushort_t* Z       = (ushort_t*)take((size_t)N_NODES * 32 * 2 + 256);
    ushort_t* t8a     = (ushort_t*)take((size_t)N_NODES * 8 * 2 + 256);
    ushort_t* t8b     = (ushort_t*)take((size_t)N_NODES * 8 * 2 + 256);

    hipMemsetAsync(cnts, 0, (size_t)N_NODES * 4, stream);

    const int EB = (N_EDGES + 255) / 256;   // 3125

    edge_mlp_kernel<<<EB, 256, 0, stream>>>(ea, x, ei, W1, b1, W2, b2, xb, cnts, bucket8);
    degdinv_kernel<<<NWB, 256, 0, stream>>>(cnts, bucket8, dinv);
    rescale_kernel<<<NWB, 256, 0, stream>>>(cnts, dinv, bucket8, bucket4);

    // ---- layer 0: 16 -> 64, relu (pre-multiply form) ----
    prop_kernel<NFEAT><<<PPB, 256, 0, stream>>>(xb, g1, cnts, bucket4);
    prop_kernel<NFEAT><<<PPB, 256, 0, stream>>>(g1, g2, cnts, bucket4);
    prop_kernel<NFEAT><<<PPB, 256, 0, stream>>>(g2, g3, cnts, bucket4);
    gemm4_kernel<NFEAT, HID, 1><<<PGB, 256, 0, stream>>>(
        xb, g1, g2, g3, Wf, bf, curA);

    // ---- mid layers: 64 -> 64, relu (ping-pong curA/curB) ----
    ushort_t* cin = curA;
    ushort_t* cot = curB;
    for (int L = 0; L < NMID; ++L) {
        prop_kernel<HID><<<PPB, 256, 0, stream>>>(cin, g1, cnts, bucket4);
        prop_kernel<HID><<<PPB, 256, 0, stream>>>(g1, g2, cnts, bucket4);
        prop_kernel<HID><<<PPB, 256, 0, stream>>>(g2, g3, cnts, bucket4);
        gemm4_kernel<HID, HID, 1><<<PGB, 256, 0, stream>>>(
            cin, g1, g2, g3, Wm + (size_t)L * 4 * HID * HID, bm + L * HID, cot);
        ushort_t* t = cin; cin = cot; cot = t;
    }

    // ---- last layer (Horner): Z = [z0+b|z1|z2|z3]; out = z0 + A(z1 + A(z2 + A z3)) ----
    gemmL_kernel<<<PGB, 256, 0, stream>>>(cin, Wl, bl, Z);
    prop8_kernel<0><<<PPB, 256, 0, stream>>>(Z, 32, 24, Z, 32, 16, t8a, nullptr, cnts, bucket4);
    prop8_kernel<0><<<PPB, 256, 0, stream>>>(t8a, 8, 0, Z, 32, 8, t8b, nullptr, cnts, bucket4);
    prop8_kernel<1><<<PPB, 256, 0, stream>>>(t8b, 8, 0, Z, 32, 0, nullptr, (float*)d_out, cnts, bucket4);
}

// Round 5
// 403.099 us; speedup vs baseline: 1.2033x; 1.2033x over previous
//
#include <hip/hip_runtime.h>
#include <stdint.h>

#define N_NODES 50000
#define N_EDGES 800000
#define NFEAT   16
#define EFEAT   8
#define HID     64
#define OUTF    8
#define NMID    2
#define NX      (N_NODES * NFEAT)
#define NPW     16                                     // nodes per wave (gemm kernels)
#define CAP     64                                     // bucket capacity (max deg ~45)
#define PGB     ((N_NODES + 4 * NPW - 1) / (4 * NPW))  // 782 blocks (gemm)
#define PPB     ((N_NODES + 15) / 16)                  // 3125 blocks (prop: 4 nodes/wave)
#define NWB     ((N_NODES + 3) / 4)                    // 12500 blocks (wave-per-node)

typedef unsigned short ushort_t;
typedef unsigned int   uint_t;
typedef unsigned long long ull_t;
typedef __bf16 bf16x8 __attribute__((ext_vector_type(8)));
typedef float  f32x4  __attribute__((ext_vector_type(4)));

__device__ __forceinline__ float b2f(ushort_t u) {
    return __uint_as_float(((uint_t)u) << 16);
}
__device__ __forceinline__ ushort_t f2b(float f) {
    uint_t u = __float_as_uint(f);
    return (ushort_t)((u + 0x7fffu + ((u >> 16) & 1u)) >> 16);
}
// fp16 (IEEE half) pack/unpack via native _Float16
__device__ __forceinline__ float h2f(ushort_t u) {
    union { ushort_t u; _Float16 h; } c; c.u = u; return (float)c.h;
}
__device__ __forceinline__ ushort_t f2h(float f) {
    union { ushort_t u; _Float16 h; } c; c.h = (_Float16)f; return c.u;
}

// ---------- edge MLP (1 edge/thread) + fused x->bf16 + 8B {ew,src} scatter ----------
// W1/b1/W2/b2 are wave-uniform -> s_load + SGPR-operand v_fma (no LDS).
// Bucket entries are 8B {fp32 ew | u32 src}: scattered-write line traffic is the
// same (one 64B line per edge either way; measured WRITE_SIZE 51.5 vs 52.6 MB),
// and it removes ALL random ew/ei gathers from degdinv/rescale.
__global__ __launch_bounds__(256) void edge_mlp_kernel(
    const float* __restrict__ ea, const float* __restrict__ x,
    const int* __restrict__ ei,
    const float* __restrict__ W1, const float* __restrict__ b1,
    const float* __restrict__ W2, const float* __restrict__ b2,
    ushort_t* __restrict__ xb,
    int* __restrict__ cnts, ull_t* __restrict__ bucket8)
{
    int tid = threadIdx.x;
    int e = blockIdx.x * 256 + tid;          // grid covers N_EDGES == NX exactly
    if (e >= N_EDGES) return;

    // atomic first: its round trip hides under the MLP below
    int d = ei[N_EDGES + e];
    int pos = atomicAdd(&cnts[d], 1);
    int sn = ei[e];                          // src, linear read

    xb[e] = f2b(x[e]);                       // fused x convert (same index space)

    // ---- MLP: fp32 exact, SGPR weights ----
    float4 v0 = ((const float4*)ea)[2 * e];
    float4 v1 = ((const float4*)ea)[2 * e + 1];
    float a[8] = {v0.x, v0.y, v0.z, v0.w, v1.x, v1.y, v1.z, v1.w};

    float h[HID];
    #pragma unroll
    for (int j = 0; j < HID; ++j) h[j] = b1[j];          // uniform -> s_load

    #pragma unroll
    for (int i = 0; i < EFEAT; ++i) {
        float ai = a[i];
        #pragma unroll
        for (int j = 0; j < HID; ++j)
            h[j] = fmaf(ai, W1[i * HID + j], h[j]);      // uniform W1 -> SGPR operand
    }

    float acc = b2[0];
    #pragma unroll
    for (int j = 0; j < HID; ++j)
        acc = fmaf(fmaxf(h[j], 0.f), W2[j], acc);        // uniform W2 -> SGPR operand

    if (pos < CAP)
        bucket8[(size_t)d * CAP + pos] =
            (((ull_t)__float_as_uint(acc)) << 32) | (uint_t)sn;
}

// ---------- deg (fp32-exact sum of ew, linear bucket8 read) -> dinv ----------
__global__ __launch_bounds__(256) void degdinv_kernel(
    int* __restrict__ cnts, const ull_t* __restrict__ bucket8,
    float* __restrict__ dinv)
{
    int tid = threadIdx.x;
    int n = blockIdx.x * 4 + (tid >> 6);
    int lane = tid & 63;
    if (n >= N_NODES) return;
    int c = cnts[n]; if (c > CAP) c = CAP;
    float w = 0.f;
    if (lane < c)
        w = __uint_as_float((uint_t)(bucket8[(size_t)n * CAP + lane] >> 32));
    #pragma unroll
    for (int o = 32; o; o >>= 1) w += __shfl_down(w, o, 64);
    if (lane == 0) {
        cnts[n] = c;
        dinv[n] = (w > 0.f) ? (1.f / sqrtf(w)) : 0.f;
    }
}

// ---------- rescale: bucket8 (linear) -> bucket4 (fp16 norm << 16 | u16 src) ----------
__global__ __launch_bounds__(256) void rescale_kernel(
    const int* __restrict__ cnts, const float* __restrict__ dinv,
    const ull_t* __restrict__ bucket8, uint_t* __restrict__ bucket4)
{
    int tid = threadIdx.x;
    int n = blockIdx.x * 4 + (tid >> 6);
    int lane = tid & 63;
    if (n >= N_NODES) return;
    int c = cnts[n];
    float dn = dinv[n];
    if (lane < c) {
        ull_t q = bucket8[(size_t)n * CAP + lane];
        uint_t s = (uint_t)q;                           // src < 50000 < 65536 ✓
        float ewv = __uint_as_float((uint_t)(q >> 32));
        float nv = dinv[s] * ewv * dn;
        nv = fminf(fmaxf(nv, -60000.f), 60000.f);       // fp16 range guard
        bucket4[(size_t)n * CAP + lane] = (((uint_t)f2h(nv)) << 16) | s;
    }
}

// ---------- pure propagation: 4 nodes/wave (widths 64 and 16), 4B entries ----------
// Round-3 structure (verified fastest): branchless padded edge loops (zero
// bucket word -> nv = 0.0 -> no-op FMA), all 4 nodes interleaved per j-step so
// 16 independent unguarded gathers are in flight. NO explicit multi-stage
// pipeline: under __launch_bounds__(256,6) the VGPR cap is ~85 and a 2-deep
// named-buffer pipeline spills to scratch (measured +70us regression in R4).
template<int W>
__global__ __launch_bounds__(256, 6) void prop_kernel(
    const ushort_t* __restrict__ gsrc, ushort_t* __restrict__ gout,
    const int* __restrict__ cnts, const uint_t* __restrict__ bucket)
{
    int tid = threadIdx.x;
    int wv = tid >> 6, lane = tid & 63;
    int nb = (blockIdx.x * 4 + wv) * 4;
    if (nb >= N_NODES) return;

    int cv = (lane < 4) ? cnts[nb + lane] : 0;
    int c0 = __builtin_amdgcn_readlane(cv, 0);
    int c1 = __builtin_amdgcn_readlane(cv, 1);
    int c2 = __builtin_amdgcn_readlane(cv, 2);
    int c3 = __builtin_amdgcn_readlane(cv, 3);
    int cm = max(max(c0, c1), max(c2, c3));

    uint_t p0 = 0, p1 = 0, p2 = 0, p3 = 0;
    if (lane < c0) p0 = bucket[(size_t)(nb + 0) * CAP + lane];
    if (lane < c1) p1 = bucket[(size_t)(nb + 1) * CAP + lane];
    if (lane < c2) p2 = bucket[(size_t)(nb + 2) * CAP + lane];
    if (lane < c3) p3 = bucket[(size_t)(nb + 3) * CAP + lane];

    if (W == 64) {
        float s[4][4];
        #pragma unroll
        for (int n = 0; n < 4; ++n)
            #pragma unroll
            for (int k = 0; k < 4; ++k) s[n][k] = 0.f;

        // j <= 60, k <= 3 -> readlane index <= 63, always valid
        for (int j = 0; j < cm; j += 4) {
            float hv[4][4], nv[4][4];
            #pragma unroll
            for (int k = 0; k < 4; ++k) {
                int pe0 = __builtin_amdgcn_readlane((int)p0, j + k);
                int pe1 = __builtin_amdgcn_readlane((int)p1, j + k);
                int pe2 = __builtin_amdgcn_readlane((int)p2, j + k);
                int pe3 = __builtin_amdgcn_readlane((int)p3, j + k);
                nv[0][k] = h2f((ushort_t)(((uint_t)pe0) >> 16));
                nv[1][k] = h2f((ushort_t)(((uint_t)pe1) >> 16));
                nv[2][k] = h2f((ushort_t)(((uint_t)pe2) >> 16));
                nv[3][k] = h2f((ushort_t)(((uint_t)pe3) >> 16));
                hv[0][k] = b2f(gsrc[(size_t)(pe0 & 0xffff) * 64 + lane]);
                hv[1][k] = b2f(gsrc[(size_t)(pe1 & 0xffff) * 64 + lane]);
                hv[2][k] = b2f(gsrc[(size_t)(pe2 & 0xffff) * 64 + lane]);
                hv[3][k] = b2f(gsrc[(size_t)(pe3 & 0xffff) * 64 + lane]);
            }
            #pragma unroll
            for (int n = 0; n < 4; ++n)
                #pragma unroll
                for (int k = 0; k < 4; ++k)
                    s[n][k] = fmaf(hv[n][k], nv[n][k], s[n][k]);
        }

        #pragma unroll
        for (int n = 0; n < 4; ++n) {
            float v = (s[n][0] + s[n][1]) + (s[n][2] + s[n][3]);
            gout[(size_t)(nb + n) * 64 + lane] = f2b(v);
        }
    } else {
        const int il = lane & 15;
        const int quad = lane >> 4;
        float s0 = 0.f, s1 = 0.f, s2 = 0.f, s3 = 0.f;

        // j <= 60 (multiple of 4, j < cm <= 64), quad <= 3 -> jq <= 63
        #pragma unroll 2
        for (int j = 0; j < cm; j += 4) {
            int jq = j + quad;
            int w0 = __shfl((int)p0, jq, 64);
            int w1 = __shfl((int)p1, jq, 64);
            int w2 = __shfl((int)p2, jq, 64);
            int w3 = __shfl((int)p3, jq, 64);
            float h0 = b2f(gsrc[(size_t)(w0 & 0xffff) * 16 + il]);
            float h1 = b2f(gsrc[(size_t)(w1 & 0xffff) * 16 + il]);
            float h2 = b2f(gsrc[(size_t)(w2 & 0xffff) * 16 + il]);
            float h3 = b2f(gsrc[(size_t)(w3 & 0xffff) * 16 + il]);
            s0 = fmaf(h0, h2f((ushort_t)(((uint_t)w0) >> 16)), s0);
            s1 = fmaf(h1, h2f((ushort_t)(((uint_t)w1) >> 16)), s1);
            s2 = fmaf(h2, h2f((ushort_t)(((uint_t)w2) >> 16)), s2);
            s3 = fmaf(h3, h2f((ushort_t)(((uint_t)w3) >> 16)), s3);
        }

        s0 += __shfl_xor(s0, 16, 64); s0 += __shfl_xor(s0, 32, 64);
        s1 += __shfl_xor(s1, 16, 64); s1 += __shfl_xor(s1, 32, 64);
        s2 += __shfl_xor(s2, 16, 64); s2 += __shfl_xor(s2, 32, 64);
        s3 += __shfl_xor(s3, 16, 64); s3 += __shfl_xor(s3, 32, 64);
        if (lane < 16) {
            gout[(size_t)(nb + 0) * 16 + lane] = f2b(s0);
            gout[(size_t)(nb + 1) * 16 + lane] = f2b(s1);
            gout[(size_t)(nb + 2) * 16 + lane] = f2b(s2);
            gout[(size_t)(nb + 3) * 16 + lane] = f2b(s3);
        }
    }
}

// ---------- width-8 Horner propagation: out[n] = A·gsrc + add  (octet per edge) ----------
// Round-3 branchless interleaved structure.
template<int F32OUT>
__global__ __launch_bounds__(256, 8) void prop8_kernel(
    const ushort_t* __restrict__ gsrc, int GS, int GO,
    const ushort_t* __restrict__ add, int AS, int AO,
    ushort_t* __restrict__ outb, float* __restrict__ outf,
    const int* __restrict__ cnts, const uint_t* __restrict__ bucket)
{
    int tid = threadIdx.x;
    int wv = tid >> 6, lane = tid & 63;
    int nb = (blockIdx.x * 4 + wv) * 4;
    if (nb >= N_NODES) return;
    const int oct = lane >> 3, il = lane & 7;

    int cv = (lane < 4) ? cnts[nb + lane] : 0;
    int c0 = __builtin_amdgcn_readlane(cv, 0);
    int c1 = __builtin_amdgcn_readlane(cv, 1);
    int c2 = __builtin_amdgcn_readlane(cv, 2);
    int c3 = __builtin_amdgcn_readlane(cv, 3);
    int cm = max(max(c0, c1), max(c2, c3));

    uint_t p0 = 0, p1 = 0, p2 = 0, p3 = 0;
    if (lane < c0) p0 = bucket[(size_t)(nb + 0) * CAP + lane];
    if (lane < c1) p1 = bucket[(size_t)(nb + 1) * CAP + lane];
    if (lane < c2) p2 = bucket[(size_t)(nb + 2) * CAP + lane];
    if (lane < c3) p3 = bucket[(size_t)(nb + 3) * CAP + lane];

    float s0 = 0.f, s1 = 0.f, s2 = 0.f, s3 = 0.f;

    // j <= 56 (multiple of 8, j < cm <= 64), oct <= 7 -> jo <= 63
    #pragma unroll 2
    for (int j = 0; j < cm; j += 8) {
        int jo = j + oct;
        int w0 = __shfl((int)p0, jo, 64);
        int w1 = __shfl((int)p1, jo, 64);
        int w2 = __shfl((int)p2, jo, 64);
        int w3 = __shfl((int)p3, jo, 64);
        float h0 = b2f(gsrc[(size_t)(w0 & 0xffff) * GS + GO + il]);
        float h1 = b2f(gsrc[(size_t)(w1 & 0xffff) * GS + GO + il]);
        float h2 = b2f(gsrc[(size_t)(w2 & 0xffff) * GS + GO + il]);
        float h3 = b2f(gsrc[(size_t)(w3 & 0xffff) * GS + GO + il]);
        s0 = fmaf(h0, h2f((ushort_t)(((uint_t)w0) >> 16)), s0);
        s1 = fmaf(h1, h2f((ushort_t)(((uint_t)w1) >> 16)), s1);
        s2 = fmaf(h2, h2f((ushort_t)(((uint_t)w2) >> 16)), s2);
        s3 = fmaf(h3, h2f((ushort_t)(((uint_t)w3) >> 16)), s3);
    }

    #define FIN(sN, n)                                                               \
        {                                                                            \
            float s = sN;                                                            \
            s += __shfl_xor(s, 8, 64);                                               \
            s += __shfl_xor(s, 16, 64);                                              \
            s += __shfl_xor(s, 32, 64);                                              \
            if (lane < 8) {                                                          \
                float v = s + b2f(add[(size_t)(nb + n) * AS + AO + lane]);           \
                if (F32OUT) outf[(size_t)(nb + n) * 8 + lane] = v;                   \
                else        outb[(size_t)(nb + n) * 8 + lane] = f2b(v);              \
            }                                                                        \
        }
    FIN(s0, 0)
    FIN(s1, 1)
    FIN(s2, 2)
    FIN(s3, 3)
    #undef FIN
}

// ---------- dense 4-source MFMA GEMM: out = act(bias + sum_s src_s @ W_s) ----------
template<int SRCW, int COUT, int ACT>
__global__ __launch_bounds__(256, 4) void gemm4_kernel(
    const ushort_t* __restrict__ s0, const ushort_t* __restrict__ s1,
    const ushort_t* __restrict__ s2, const ushort_t* __restrict__ s3,
    const float* __restrict__ Wg,    // (4, SRCW, COUT) fp32
    const float* __restrict__ bias,
    ushort_t* __restrict__ outb)
{
    constexpr int NCH = (SRCW == 16) ? 2 : 8;
    constexpr int NT  = (COUT + 15) / 16;
    __shared__ __align__(16) ushort_t Bp[NCH * NT * 512];

    int tid = threadIdx.x;
    for (int idx = tid; idx < NCH * NT * 512; idx += 256) {
        int f = idx >> 9;
        int l = (idx >> 3) & 63, j = idx & 7;
        int ch = f / NT, nt = f - ch * NT;
        int kk = ((l >> 4) << 3) + j;       // 0..31
        int n = nt * 16 + (l & 15);
        int widx, krow;
        if (SRCW == 16) { widx = 2 * ch + (kk >> 4); krow = kk & 15; }
        else            { widx = ch >> 1;            krow = ((ch & 1) << 5) + kk; }
        float v = (n < COUT) ? Wg[((size_t)widx * SRCW + krow) * COUT + n] : 0.f;
        Bp[idx] = f2b(v);
    }
    __syncthreads();

    int wv = tid >> 6, lane = tid & 63;
    int node_base = (blockIdx.x * 4 + wv) * NPW;
    if (node_base >= N_NODES) return;
    int m = lane & 15, quad = lane >> 4;

    const ushort_t* srcs[4] = {s0, s1, s2, s3};
    bf16x8 a[NCH];
    #pragma unroll
    for (int ch = 0; ch < NCH; ++ch) {
        const ushort_t* sp;
        size_t off;
        if (SRCW == 16) {
            sp = (quad < 2) ? srcs[2 * ch] : srcs[2 * ch + 1];
            off = (size_t)(node_base + m) * 16 + (quad & 1) * 8;
        } else {
            sp = srcs[ch >> 1];
            off = (size_t)(node_base + m) * 64 + ((ch & 1) << 5) + quad * 8;
        }
        a[ch] = *(const bf16x8*)(sp + off);
    }

    #pragma unroll
    for (int nt = 0; nt < NT; ++nt) {
        float bv = bias[(nt * 16 + m) & (COUT - 1)];
        f32x4 c = {bv, bv, bv, bv};
        #pragma unroll
        for (int ch = 0; ch < NCH; ++ch) {
            bf16x8 b = *(const bf16x8*)&Bp[((ch * NT + nt) * 64 + lane) * 8];
            c = __builtin_amdgcn_mfma_f32_16x16x32_bf16(a[ch], b, c, 0, 0, 0);
        }
        #pragma unroll
        for (int r = 0; r < 4; ++r) {
            int row = node_base + quad * 4 + r;
            float v = ACT ? fmaxf(c[r], 0.f) : c[r];
            outb[(size_t)row * COUT + nt * 16 + m] = f2b(v);
        }
    }
}

// ---------- last-layer Z pack: Z[n][4*8] = [cin@Wl0 + bl | cin@Wl1 | cin@Wl2 | cin@Wl3] ----------
__global__ __launch_bounds__(256, 4) void gemmL_kernel(
    const ushort_t* __restrict__ src,   // 50k x 64 bf16
    const float* __restrict__ Wl,       // (4, 64, 8) fp32
    const float* __restrict__ bl,       // (8)
    ushort_t* __restrict__ Z)           // 50k x 32 bf16
{
    __shared__ __align__(16) ushort_t Bp[2 * 2 * 512];

    int tid = threadIdx.x;
    for (int idx = tid; idx < 2048; idx += 256) {
        int f = idx >> 9;                   // 0..3
        int ch = f >> 1, nt = f & 1;
        int l = (idx >> 3) & 63, j = idx & 7;
        int kg = ch * 32 + ((l >> 4) << 3) + j;   // 0..63
        int n = nt * 16 + (l & 15);               // 0..31
        int widx = n >> 3, col = n & 7;
        Bp[idx] = f2b(Wl[((size_t)widx * 64 + kg) * 8 + col]);
    }
    __syncthreads();

    int wv = tid >> 6, lane = tid & 63;
    int node_base = (blockIdx.x * 4 + wv) * NPW;
    if (node_base >= N_NODES) return;
    int m = lane & 15, quad = lane >> 4;

    bf16x8 a[2];
    #pragma unroll
    for (int ch = 0; ch < 2; ++ch)
        a[ch] = *(const bf16x8*)(src + (size_t)(node_base + m) * 64 + ch * 32 + quad * 8);

    #pragma unroll
    for (int nt = 0; nt < 2; ++nt) {
        int n = nt * 16 + m;
        float bv = (n < 8) ? bl[n] : 0.f;   // bias folded into z0 block
        f32x4 c = {bv, bv, bv, bv};
        #pragma unroll
        for (int ch = 0; ch < 2; ++ch) {
            bf16x8 b = *(const bf16x8*)&Bp[((ch * 2 + nt) * 64 + lane) * 8];
            c = __builtin_amdgcn_mfma_f32_16x16x32_bf16(a[ch], b, c, 0, 0, 0);
        }
        #pragma unroll
        for (int r = 0; r < 4; ++r) {
            int row = node_base + quad * 4 + r;
            Z[(size_t)row * 32 + n] = f2b(c[r]);
        }
    }
}

extern "C" void kernel_launch(void* const* d_in, const int* in_sizes, int n_in,
                              void* d_out, int out_size, void* d_ws, size_t ws_size,
                              hipStream_t stream)
{
    const float* x  = (const float*)d_in[0];
    const int*   ei = (const int*)d_in[1];
    const float* ea = (const float*)d_in[2];
    const float* W1 = (const float*)d_in[3];
    const float* b1 = (const float*)d_in[4];
    const float* W2 = (const float*)d_in[5];
    const float* b2 = (const float*)d_in[6];
    const float* Wf = (const float*)d_in[7];
    const float* bf = (const float*)d_in[8];
    const float* Wm = (const float*)d_in[9];
    const float* bm = (const float*)d_in[10];
    const float* Wl = (const float*)d_in[11];
    const float* bl = (const float*)d_in[12];

    char* ws = (char*)d_ws;
    size_t off = 0;
    auto take = [&](size_t bytes) -> char* {
        char* p = ws + off;
        off = (off + bytes + 255) & ~(size_t)255;
        return p;
    };
    int*      cnts    = (int*)take((size_t)N_NODES * 4);
    float*    dinv    = (float*)take((size_t)N_NODES * 4);
    ull_t*    bucket8 = (ull_t*)take((size_t)N_NODES * CAP * 8);
    uint_t*   bucket4 = (uint_t*)take((size_t)N_NODES * CAP * 4);
    ushort_t* xb      = (ushort_t*)take((size_t)NX * 2 + 256);
    ushort_t* g1      = (ushort_t*)take((size_t)N_NODES * HID * 2 + 256);
    ushort_t* g2      = (ushort_t*)take((size_t)N_NODES * HID * 2 + 256);
    ushort_t* g3      = (ushort_t*)take((size_t)N_NODES * HID * 2 + 256);
    ushort_t* curA    = (ushort_t*)take((size_t)N_NODES * HID * 2 + 256);
    ushort_t* curB    = (ushort_t*)take((size_t)N_NODES * HID * 2 + 256);
    ushort_t* Z       = (ushort_t*)take((size_t)N_NODES * 32 * 2 + 256);
    ushort_t* t8a     = (ushort_t*)take((size_t)N_NODES * 8 * 2 + 256);
    ushort_t* t8b     = (ushort_t*)take((size_t)N_NODES * 8 * 2 + 256);

    hipMemsetAsync(cnts, 0, (size_t)N_NODES * 4, stream);

    const int EB = (N_EDGES + 255) / 256;   // 3125

    edge_mlp_kernel<<<EB, 256, 0, stream>>>(ea, x, ei, W1, b1, W2, b2, xb, cnts, bucket8);
    degdinv_kernel<<<NWB, 256, 0, stream>>>(cnts, bucket8, dinv);
    rescale_kernel<<<NWB, 256, 0, stream>>>(cnts, dinv, bucket8, bucket4);

    // ---- layer 0: 16 -> 64, relu (pre-multiply form) ----
    prop_kernel<NFEAT><<<PPB, 256, 0, stream>>>(xb, g1, cnts, bucket4);
    prop_kernel<NFEAT><<<PPB, 256, 0, stream>>>(g1, g2, cnts, bucket4);
    prop_kernel<NFEAT><<<PPB, 256, 0, stream>>>(g2, g3, cnts, bucket4);
    gemm4_kernel<NFEAT, HID, 1><<<PGB, 256, 0, stream>>>(
        xb, g1, g2, g3, Wf, bf, curA);

    // ---- mid layers: 64 -> 64, relu (ping-pong curA/curB) ----
    ushort_t* cin = curA;
    ushort_t* cot = curB;
    for (int L = 0; L < NMID; ++L) {
        prop_kernel<HID><<<PPB, 256, 0, stream>>>(cin, g1, cnts, bucket4);
        prop_kernel<HID><<<PPB, 256, 0, stream>>>(g1, g2, cnts, bucket4);
        prop_kernel<HID><<<PPB, 256, 0, stream>>>(g2, g3, cnts, bucket4);
        gemm4_kernel<HID, HID, 1><<<PGB, 256, 0, stream>>>(
            cin, g1, g2, g3, Wm + (size_t)L * 4 * HID * HID, bm + L * HID, cot);
        ushort_t* t = cin; cin = cot; cot = t;
    }

    // ---- last layer (Horner): Z = [z0+b|z1|z2|z3]; out = z0 + A(z1 + A(z2 + A z3)) ----
    gemmL_kernel<<<PGB, 256, 0, stream>>>(cin, Wl, bl, Z);
    prop8_kernel<0><<<PPB, 256, 0, stream>>>(Z, 32, 24, Z, 32, 16, t8a, nullptr, cnts, bucket4);
    prop8_kernel<0><<<PPB, 256, 0, stream>>>(t8a, 8, 0, Z, 32, 8, t8b, nullptr, cnts, bucket4);
    prop8_kernel<1><<<PPB, 256, 0, stream>>>(t8b, 8, 0, Z, 32, 0, nullptr, (float*)d_out, cnts, bucket4);
}